// Round 7
// baseline (89.021 us; speedup 1.0000x reference)
//
#include <hip/hip_runtime.h>

// Steered 3x3 conv as per-pixel GEMM (K=256 = 64ch x 4 feats) via bf16 MFMA.
// v7: NO LDS, NO barriers. Taps read directly from global (L1/L2/L3-resident);
// per-lane 32-bit offsets precomputed (global_load = voffset + SGPR base);
// packed-f32 (v_pk_*) feature math over the channel pair; weights repacked so
// A-fragment loads are fully coalesced. Rationale: r6 counters showed a 5x
// stall factor from the 2-barrier-per-chunk staging skeleton (MfmaUtil 6.5%,
// VALUBusy 38%, both idle) -- so remove the skeleton, not tune it.
// B-frag: lane l -> col = l&31 (pixel), k = 16*kc + 8*(l>>5) + r  (verified r2)
// C/D:    col = lane&31, row(o) = (r&3) + 8*(r>>2) + 4*(lane>>5)  (verified r2)

typedef __bf16 bf16x8 __attribute__((ext_vector_type(8)));
typedef float  f32x16 __attribute__((ext_vector_type(16)));
typedef float  f32x2  __attribute__((ext_vector_type(2)));

#define HH 128
#define WW 128
#define HW 16384

// Repack weights f32[o][k] -> bf16 grouped per MFMA A-fragment:
// wb[((kcg*2+hx)*64 + o)*8 + r] = bf16(wt[o][kcg*16 + hx*8 + r])
// so lane pc's 16B A-load is contiguous and coalesced across lanes.
__global__ void wt_repack(const float* __restrict__ wt,
                          unsigned short* __restrict__ wb) {
    int i = blockIdx.x * 256 + threadIdx.x;   // i = o*256 + k
    int o = i >> 8, k = i & 255;
    union { float f; unsigned u; } v; v.f = wt[i];
    unsigned short b = (unsigned short)((v.u + 0x7FFF + ((v.u >> 16) & 1)) >> 16);
    int kcg = k >> 4, hxx = (k >> 3) & 1, r = k & 7;
    wb[((kcg * 2 + hxx) * 64 + o) * 8 + r] = b;
}

__global__ __launch_bounds__(256, 4) void steered_conv(
    const float* __restrict__ x, const float* __restrict__ theta,
    const unsigned short* __restrict__ wb, const float* __restrict__ bias,
    float* __restrict__ out)
{
    const int tid  = threadIdx.x;
    const int wid  = tid >> 6, lane = tid & 63;
    const int pc   = lane & 31, hx = lane >> 5;

    // bijective XCD swizzle: 1024 blocks, 128/XCD = 2 whole images
    const int bb  = blockIdx.x;
    const int swz = (bb & 7) * 128 + (bb >> 3);
    const int n  = swz >> 6;
    const int ty = (swz >> 2) & 15, tx = swz & 3;
    const int hA = ty * 8 + wid * 2;       // this wave's first pixel row
    const int w  = tx * 32 + pc;           // this lane's pixel column

    // ---- per-pixel harmonics for the wave's two rows ----
    float s1a, c1a, s1b, c1b;
    __sincosf(6.2831853071795864769f * theta[(n * HH + hA) * WW + w], &s1a, &c1a);
    __sincosf(6.2831853071795864769f * theta[(n * HH + hA + 1) * WW + w], &s1b, &c1b);
    const float c2a = 2.f * c1a * c1a - 1.f, s2a = 2.f * s1a * c1a;
    const float c2b = 2.f * c1b * c1b - 1.f, s2b = 2.f * s1b * c1b;

    // ---- hoisted tap offsets (elements) + validity masks ----
    const int wm = w > 0 ? w - 1 : 0;
    const int wp = w < WW - 1 ? w + 1 : WW - 1;
    const bool lval = (w > 0), rval = (w < WW - 1);
    int offL[4], offC[4], offR[4];
    bool rv[4];
    #pragma unroll
    for (int r = 0; r < 4; ++r) {
        int gh = hA - 1 + r;
        rv[r] = (unsigned)gh < (unsigned)HH;
        int ghc = gh < 0 ? 0 : (gh > HH - 1 ? HH - 1 : gh);
        offL[r] = ghc * WW + wm;
        offC[r] = ghc * WW + w;
        offR[r] = ghc * WW + wp;
    }

    f32x16 acc00, acc01, acc10, acc11;
    #pragma unroll
    for (int r = 0; r < 16; ++r) { acc00[r]=0.f; acc01[r]=0.f; acc10[r]=0.f; acc11[r]=0.f; }

    const float RS  = 0.35355339059327373f;   // sqrt(2)/4
    const float HMR = 0.14644660940672627f;   // 0.5 - RS

    // channel base for this lane-half: channels kcg*4 + hx*2 (+1)
    const float* xbase = x + (size_t)n * 64 * HW + (size_t)(hx * 2) * HW;

    #pragma unroll 1
    for (int kcg = 0; kcg < 16; ++kcg) {
        const float* p0 = xbase + (size_t)(kcg * 4) * HW;   // uniform (SGPR)
        const float* p1 = p0 + HW;
        f32x2 S[4], D[4], C[4];
        #pragma unroll
        for (int r = 0; r < 4; ++r) {
            const float l0 = p0[offL[r]], c0 = p0[offC[r]], q0 = p0[offR[r]];
            const float l1 = p1[offL[r]], c1 = p1[offC[r]], q1 = p1[offR[r]];
            const bool v = rv[r];
            const bool vl = v && lval, vr = v && rval;
            f32x2 L  = { vl ? l0 : 0.f, vl ? l1 : 0.f };
            f32x2 Cc = { v  ? c0 : 0.f, v  ? c1 : 0.f };
            f32x2 R  = { vr ? q0 : 0.f, vr ? q1 : 0.f };
            S[r] = L + Cc + R;
            D[r] = R - L;
            C[r] = Cc;
        }
        bf16x8 b0, b1;
        {   // pixel row hA (tap rows 0,1,2)
            f32x2 F1 = RS * (S[0] + S[2] + (S[1] - C[1]));
            f32x2 B2 = RS * (D[0] + D[2]) + 0.5f * D[1];
            f32x2 B3 = RS * (S[2] - S[0]) + HMR * (C[2] - C[0]);
            f32x2 B4 = 0.5f * (S[1] - C[1] - (C[0] + C[2]));
            f32x2 B5 = 0.5f * (D[2] - D[0]);
            f32x2 F2 = c1a * B2 + s1a * B3;
            f32x2 F3 = c2a * B4 + s2a * B5;
            b0[0]=(__bf16)C[1].x; b0[1]=(__bf16)F1.x; b0[2]=(__bf16)F2.x; b0[3]=(__bf16)F3.x;
            b0[4]=(__bf16)C[1].y; b0[5]=(__bf16)F1.y; b0[6]=(__bf16)F2.y; b0[7]=(__bf16)F3.y;
        }
        {   // pixel row hA+1 (tap rows 1,2,3)
            f32x2 F1 = RS * (S[1] + S[3] + (S[2] - C[2]));
            f32x2 B2 = RS * (D[1] + D[3]) + 0.5f * D[2];
            f32x2 B3 = RS * (S[3] - S[1]) + HMR * (C[3] - C[1]);
            f32x2 B4 = 0.5f * (S[2] - C[2] - (C[1] + C[3]));
            f32x2 B5 = 0.5f * (D[3] - D[1]);
            f32x2 F2 = c1b * B2 + s1b * B3;
            f32x2 F3 = c2b * B4 + s2b * B5;
            b1[0]=(__bf16)C[2].x; b1[1]=(__bf16)F1.x; b1[2]=(__bf16)F2.x; b1[3]=(__bf16)F3.x;
            b1[4]=(__bf16)C[2].y; b1[5]=(__bf16)F1.y; b1[6]=(__bf16)F2.y; b1[7]=(__bf16)F3.y;
        }
        const unsigned short* wr = wb + ((kcg * 2 + hx) * 64 + pc) * 8;
        const bf16x8 A0 = *(const bf16x8*)wr;
        const bf16x8 A1 = *(const bf16x8*)(wr + 32 * 8);
        acc00 = __builtin_amdgcn_mfma_f32_32x32x16_bf16(A0, b0, acc00, 0, 0, 0);
        acc01 = __builtin_amdgcn_mfma_f32_32x32x16_bf16(A1, b0, acc01, 0, 0, 0);
        acc10 = __builtin_amdgcn_mfma_f32_32x32x16_bf16(A0, b1, acc10, 0, 0, 0);
        acc11 = __builtin_amdgcn_mfma_f32_32x32x16_bf16(A1, b1, acc11, 0, 0, 0);
    }

    const size_t hw = (size_t)HW;
    float* op = out + (size_t)n * 64 * hw + (size_t)hA * WW + w;
    #pragma unroll
    for (int r = 0; r < 16; ++r) {
        const int o  = (r & 3) + 8 * (r >> 2) + 4 * hx;
        const float bo = bias[o], bo2 = bias[o + 32];
        op[(size_t)o * hw]             = acc00[r] + bo;
        op[(size_t)(o + 32) * hw]      = acc01[r] + bo2;
        op[(size_t)o * hw + WW]        = acc10[r] + bo;
        op[(size_t)(o + 32) * hw + WW] = acc11[r] + bo2;
    }
}

extern "C" void kernel_launch(void* const* d_in, const int* in_sizes, int n_in,
                              void* d_out, int out_size, void* d_ws, size_t ws_size,
                              hipStream_t stream) {
    const float* x     = (const float*)d_in[0];
    const float* theta = (const float*)d_in[1];
    const float* wt    = (const float*)d_in[2];
    const float* bias  = (const float*)d_in[3];
    float* out = (float*)d_out;
    unsigned short* wb = (unsigned short*)d_ws;   // 32 KB bf16 weights (repacked)

    wt_repack<<<64, 256, 0, stream>>>(wt, wb);

    steered_conv<<<1024, 256, 0, stream>>>(x, theta, wb, bias, out);
}

// Round 8
// 41.914 us; speedup vs baseline: 2.1239x; 2.1239x over previous
//
#include <hip/hip_runtime.h>

// Steered 3x3 conv as per-pixel GEMM (K=256 = 64ch x 4 feats) via bf16 MFMA.
// v8: r6 skeleton + counted-vmcnt pipeline (T3/T4). Key insight: vmcnt is an
// IN-ORDER counter, so per-phase weight loads issued AFTER the x-DMA prefetch
// forced a full HBM drain every phase (r4/r6's hidden 5x stall). Fix: issue
// weights FIRST each phase (their consumption wait then leaves the newer
// prefetch in flight), raw s_barrier + asm vmcnt(4) instead of __syncthreads,
// 3 LDS buffers (2-phase latency cover), boundary handled by DMA skip-masks +
// one-time pre-zero (no per-chunk fix pass), full 8-phase unroll, setprio.
// B-frag: lane l -> col = l&31 (pixel), k = 16*kc + 8*(l>>5) + r  (verified r2)
// C/D:    col = lane&31, row(o) = (r&3) + 8*(r>>2) + 4*(lane>>5)  (verified r2)

typedef __bf16 bf16x8 __attribute__((ext_vector_type(8)));
typedef float  f32x16 __attribute__((ext_vector_type(16)));
typedef float  f32x4  __attribute__((ext_vector_type(4)));
typedef unsigned int u32;
typedef const __attribute__((address_space(1))) u32* gp_t;
typedef __attribute__((address_space(3))) u32* lp_t;

#define HH 128
#define WW 128
#define CHCH 8              // channels per chunk
#define NCHUNK 8
#define NBUF 3              // triple buffer: prefetch depth 2
#define RROWS 10
#define RCOLS 40
#define CHF 400             // floats per channel slot
#define CHIMG 65536         // bytes per (n,ch) plane

// Weights f32[o][k] -> bf16 grouped per MFMA A-fragment (coalesced loads):
// wb[((kcg*2+hx)*64 + o)*8 + r] = bf16(wt[o][kcg*16 + hx*8 + r])
__global__ void wt_repack(const float* __restrict__ wt,
                          unsigned short* __restrict__ wb) {
    int i = blockIdx.x * 256 + threadIdx.x;   // i = o*256 + k
    int o = i >> 8, k = i & 255;
    union { float f; u32 u; } v; v.f = wt[i];
    unsigned short b = (unsigned short)((v.u + 0x7FFF + ((v.u >> 16) & 1)) >> 16);
    int kcg = k >> 4, hxx = (k >> 3) & 1, r = k & 7;
    wb[((kcg * 2 + hxx) * 64 + o) * 8 + r] = b;
}

__global__ __launch_bounds__(256, 4) void steered_conv_mfma(
    const float* __restrict__ x, const float* __restrict__ theta,
    const unsigned short* __restrict__ wb, const float* __restrict__ bias,
    float* __restrict__ out)
{
    __shared__ __attribute__((aligned(16))) float lds[NBUF][CHCH][CHF]; // 38400 B

    const int tid = threadIdx.x;
    const int wid = tid >> 6, lane = tid & 63;
    const int pc = lane & 31, hx = lane >> 5;

    // bijective XCD swizzle: 1024 blocks, 128/XCD = 2 whole images
    const int bb = blockIdx.x;
    const int swz = (bb & 7) * 128 + (bb >> 3);
    const int n = swz >> 6;
    const int ty = (swz >> 2) & 15, tx = swz & 3;
    const int h0 = ty * 8, w0 = tx * 32;
    const int p0 = wid * 2;

    // ---- per-lane DMA constants; skip-masks now also cover OOB halo rows/cols
    //      (skipped slots stay at the pre-zeroed value) ----
    const int oA = lane * 16;
    const int rA = oA / 160;
    const int cA = oA - rA * 160;
    int ghA = h0 - 1 + rA; ghA = ghA < 0 ? 0 : (ghA > 127 ? 127 : ghA);
    int srcA = ghA * 512 + w0 * 4 - 16 + cA;
    srcA = srcA < 0 ? 0 : srcA;
    const bool skA = (w0 == 0 && cA < 16) || (w0 == 96 && cA >= 144)
                   || (h0 == 0 && rA == 0);

    const int oB = 1024 + lane * 16;
    const int rB = oB / 160;
    const int cB = oB - rB * 160;
    int ghB = h0 - 1 + rB; ghB = ghB < 0 ? 0 : (ghB > 127 ? 127 : ghB);
    int srcB = ghB * 512 + w0 * 4 - 16 + cB;
    srcB = srcB < 0 ? 0 : (srcB > CHIMG - 16 ? CHIMG - 16 : srcB);
    const bool skB = (lane >= 36) || (w0 == 0 && cB < 16) || (w0 == 96 && cB >= 144)
                   || (h0 == 120 && rB == 9);

    const char* xn = (const char*)x + (size_t)n * 64 * CHIMG;

    // ---- theta + harmonics first (its VMEM retires before the pipeline) ----
    float s1a, c1a, s1b, c1b;
    __sincosf(6.2831853071795864769f * theta[(n*HH + h0+p0)*WW + w0+pc], &s1a, &c1a);
    __sincosf(6.2831853071795864769f * theta[(n*HH + h0+p0+1)*WW + w0+pc], &s1b, &c1b);
    const float c2a = 2.f*c1a*c1a - 1.f, s2a = 2.f*s1a*c1a;
    const float c2b = 2.f*c1b*c1b - 1.f, s2b = 2.f*s1b*c1b;

    // ---- one-time pre-zero for boundary tiles (skipped DMA slots read as 0) ----
    if ((h0 == 0) | (h0 == 120) | (w0 == 0) | (w0 == 96)) {
        f32x4* z = (f32x4*)&lds[0][0][0];
        for (int i = tid; i < NBUF * CHCH * CHF / 4; i += 256)
            z[i] = f32x4{0.f, 0.f, 0.f, 0.f};
    }
    __syncthreads();

    auto stage = [&](int t) {
        const char* xc = xn + (size_t)(t * CHCH) * CHIMG;
        #pragma unroll
        for (int j = 0; j < 2; ++j) {
            const int ch = wid * 2 + j;
            const char* s = xc + ch * CHIMG;
            char* d = (char*)&lds[t % NBUF][ch][0];
            if (!skA) __builtin_amdgcn_global_load_lds((gp_t)(s + srcA), (lp_t)d, 16, 0, 0);
            if (!skB) __builtin_amdgcn_global_load_lds((gp_t)(s + srcB), (lp_t)(d + 1024), 16, 0, 0);
        }
    };

    stage(0);
    stage(1);

    f32x16 acc00, acc01, acc10, acc11;
    #pragma unroll
    for (int r = 0; r < 16; ++r) { acc00[r]=0.f; acc01[r]=0.f; acc10[r]=0.f; acc11[r]=0.f; }

    const float RS  = 0.35355339059327373f;   // sqrt(2)/4
    const float HMR = 0.14644660940672627f;   // 0.5 - RS
    const unsigned short* wbl = wb + (hx * 64 + pc) * 8;

    #pragma unroll
    for (int c = 0; c < NCHUNK; ++c) {
        // chunk c's DMA (issued 2 phases ago) is the oldest outstanding VMEM
        asm volatile("s_waitcnt vmcnt(4)" ::: "memory");
        // weight fragments: issued BEFORE this phase's prefetch so their
        // consumption wait (vmcnt(4)) leaves the prefetch in flight
        const unsigned short* wr0 = wbl + c * 2048;
        const bf16x8 A00 = *(const bf16x8*)(wr0);
        const bf16x8 A01 = *(const bf16x8*)(wr0 + 256);
        const bf16x8 A10 = *(const bf16x8*)(wr0 + 1024);
        const bf16x8 A11 = *(const bf16x8*)(wr0 + 1280);
        __builtin_amdgcn_sched_barrier(0);
        __builtin_amdgcn_s_barrier();
        if (c < NCHUNK - 2) stage(c + 2);   // WAR-safe: buf (c+2)%3 freed at barrier
        __builtin_amdgcn_sched_barrier(0);

        const float* tb = &lds[c % NBUF][0][p0 * RCOLS + pc + 3];
        #pragma unroll
        for (int kc = 0; kc < 2; ++kc) {
            bf16x8 b0, b1;
            #pragma unroll
            for (int cs = 0; cs < 2; ++cs) {
                const float* t = tb + (kc * 4 + hx * 2 + cs) * CHF;
                const float t00=t[0],   t01=t[1],   t02=t[2];
                const float t10=t[40],  t11=t[41],  t12=t[42];
                const float t20=t[80],  t21=t[81],  t22=t[82];
                const float t30=t[120], t31=t[121], t32=t[122];
                const float S0=t00+t01+t02, S1=t10+t11+t12;
                const float S2=t20+t21+t22, S3=t30+t31+t32;
                const float D0=t02-t00, D1=t12-t10, D2=t22-t20, D3=t32-t30;
                {   // pixel row p0 (staged rows 0,1,2)
                    const float F1 = RS * (S0 + S2 + S1 - t11);
                    const float B2 = RS * (D0 + D2) + 0.5f * D1;
                    const float B3 = RS * (S2 - S0) + HMR * (t21 - t01);
                    const float B4 = 0.5f * (S1 - t11 - t01 - t21);
                    const float B5 = 0.5f * (D2 - D0);
                    b0[cs*4+0] = (__bf16)t11;
                    b0[cs*4+1] = (__bf16)F1;
                    b0[cs*4+2] = (__bf16)(c1a * B2 + s1a * B3);
                    b0[cs*4+3] = (__bf16)(c2a * B4 + s2a * B5);
                }
                {   // pixel row p0+1 (staged rows 1,2,3)
                    const float F1 = RS * (S1 + S3 + S2 - t21);
                    const float B2 = RS * (D1 + D3) + 0.5f * D2;
                    const float B3 = RS * (S3 - S1) + HMR * (t31 - t11);
                    const float B4 = 0.5f * (S2 - t21 - t11 - t31);
                    const float B5 = 0.5f * (D3 - D1);
                    b1[cs*4+0] = (__bf16)t21;
                    b1[cs*4+1] = (__bf16)F1;
                    b1[cs*4+2] = (__bf16)(c1b * B2 + s1b * B3);
                    b1[cs*4+3] = (__bf16)(c2b * B4 + s2b * B5);
                }
            }
            const bf16x8 A0 = kc ? A10 : A00;
            const bf16x8 A1 = kc ? A11 : A01;
            __builtin_amdgcn_s_setprio(1);
            acc00 = __builtin_amdgcn_mfma_f32_32x32x16_bf16(A0, b0, acc00, 0, 0, 0);
            acc01 = __builtin_amdgcn_mfma_f32_32x32x16_bf16(A1, b0, acc01, 0, 0, 0);
            acc10 = __builtin_amdgcn_mfma_f32_32x32x16_bf16(A0, b1, acc10, 0, 0, 0);
            acc11 = __builtin_amdgcn_mfma_f32_32x32x16_bf16(A1, b1, acc11, 0, 0, 0);
            __builtin_amdgcn_s_setprio(0);
        }
    }

    const size_t hw = (size_t)HH * WW;
    float* op = out + (size_t)n * 64 * hw + (size_t)(h0 + p0) * WW + w0 + pc;
    #pragma unroll
    for (int r = 0; r < 16; ++r) {
        const int o = (r & 3) + 8 * (r >> 2) + 4 * hx;
        const float bo = bias[o], bo2 = bias[o + 32];
        op[(size_t)o * hw]             = acc00[r] + bo;
        op[(size_t)(o + 32) * hw]      = acc01[r] + bo2;
        op[(size_t)o * hw + WW]        = acc10[r] + bo;
        op[(size_t)(o + 32) * hw + WW] = acc11[r] + bo2;
    }
}

extern "C" void kernel_launch(void* const* d_in, const int* in_sizes, int n_in,
                              void* d_out, int out_size, void* d_ws, size_t ws_size,
                              hipStream_t stream) {
    const float* x     = (const float*)d_in[0];
    const float* theta = (const float*)d_in[1];
    const float* wt    = (const float*)d_in[2];
    const float* bias  = (const float*)d_in[3];
    float* out = (float*)d_out;
    unsigned short* wb = (unsigned short*)d_ws;   // 32 KB bf16 weights (repacked)

    wt_repack<<<64, 256, 0, stream>>>(wt, wb);

    steered_conv_mfma<<<1024, 256, 0, stream>>>(x, theta, wb, bias, out);
}